// Round 3
// baseline (99.132 us; speedup 1.0000x reference)
//
#include <hip/hip_runtime.h>

// z[l, c] = prior[0] * dic[1, 0, c]  for all l in [0, L)
//
// attention = softmax over a size-1 axis == 1.0 exactly -> output is a
// broadcast of one scaled 1024-float row. Pure write-stream kernel.
//
// R2 change vs R1: mimic fillBufferAligned's dispatch shape (it hits 6.7 TB/s
// at ~10% occupancy): 512 blocks instead of 2048 -> 2 blocks/CU, each block
// owns a contiguous 1 MiB run; x8 unroll keeps 8 independent 1 KiB stores in
// flight per wave. Fewer concurrent write streams -> better DRAM row-buffer
// locality + shorter launch ramp.

typedef float f4 __attribute__((ext_vector_type(4)));

__global__ __launch_bounds__(256) void CausalPredictor_46462956208724_kernel(
    const float* __restrict__ dic,    // [2, 1, C] flat; dic_z = dic + C
    const float* __restrict__ prior,  // [1]
    float* __restrict__ out,          // [L, C] flat
    int rows_per_block)               // rows / gridDim.x
{
    const int C4 = 256;               // float4 chunks per row; blockDim.x == 256
    const float p = prior[0];

    const f4* dz4 = reinterpret_cast<const f4*>(dic + 1024);   // dic[1:]
    f4 v = dz4[threadIdx.x];
    v *= p;

    f4* out4 = reinterpret_cast<f4*>(out);
    // Block b owns rows [b*rpb, (b+1)*rpb) -- one contiguous 1 MiB region.
    size_t base = (size_t)blockIdx.x * rows_per_block * C4 + threadIdx.x;

    #pragma unroll 8
    for (int r = 0; r < rows_per_block; ++r) {
        out4[base + (size_t)r * C4] = v;   // 4 KiB per wave-instruction, coalesced
    }
}

extern "C" void kernel_launch(void* const* d_in, const int* in_sizes, int n_in,
                              void* d_out, int out_size, void* d_ws, size_t ws_size,
                              hipStream_t stream) {
    // setup_inputs order: x, xm, Wy_w, Wy_b, Wz_w, Wz_b, dic, prior
    const float* dic   = (const float*)d_in[6];
    const float* prior = (const float*)d_in[7];
    float* out = (float*)d_out;

    const int C = 1024;
    const int rows = out_size / C;    // L = 131072

    const int grid = 512;             // 512 blocks * 256 rows = 131072 rows
    const int rows_per_block = rows / grid;
    CausalPredictor_46462956208724_kernel<<<grid, 256, 0, stream>>>(dic, prior, out, rows_per_block);
}